// Round 1
// baseline (504.879 us; speedup 1.0000x reference)
//
#include <hip/hip_runtime.h>

typedef __bf16 bf16;
typedef bf16 bf16x8 __attribute__((ext_vector_type(8)));
typedef float f32x4 __attribute__((ext_vector_type(4)));

#define B_ 4
#define T_ 4096
#define C_ 1024
#define H_ 16
#define D_ 64
#define NCH 16
#define EPS_ 1e-6f

// ---------------- cast f32 -> bf16 (vectorized, 8/thread) ----------------
__global__ void cast_kernel(const float* __restrict__ in, bf16* __restrict__ out, int n8) {
  int i = blockIdx.x * blockDim.x + threadIdx.x;
  int stride = gridDim.x * blockDim.x;
  for (; i < n8; i += stride) {
    const float4* p = (const float4*)(in + (size_t)i * 8);
    float4 v0 = p[0];
    float4 v1 = p[1];
    bf16x8 o;
    o[0] = (bf16)v0.x; o[1] = (bf16)v0.y; o[2] = (bf16)v0.z; o[3] = (bf16)v0.w;
    o[4] = (bf16)v1.x; o[5] = (bf16)v1.y; o[6] = (bf16)v1.z; o[7] = (bf16)v1.w;
    *(bf16x8*)(out + (size_t)i * 8) = o;
  }
}

// ---------------- NT GEMM: C[M][N] = A[M][K] * B[N][K]^T ----------------
// MODE 0: write bf16, apply phi (elu+1) to cols < 2*C_ (q,k parts of qkv)
// MODE 1: write f32, add bias
template <int MODE>
__global__ __launch_bounds__(256) void gemm_nt(
    const bf16* __restrict__ A, const bf16* __restrict__ Bm,
    void* __restrict__ Cout, const float* __restrict__ bias,
    int M, int N, int K, int tiles_n) {
  __shared__ bf16 As[128 * 32];
  __shared__ bf16 Bs[128 * 32];

  const int tid = threadIdx.x;
  const int lane = tid & 63;
  const int wave = tid >> 6;
  const int wm = (wave >> 1) * 64;
  const int wn = (wave & 1) * 64;

  const int tm = (blockIdx.x / tiles_n) * 128;
  const int tn = (blockIdx.x % tiles_n) * 128;

  // staging: thread covers 32B of A-tile and 32B of B-tile
  // row = tid/2 (128 rows), two 16B chunks at chunk index scol, scol+1
  const int srow = tid >> 1;
  const int scol = (tid & 1) * 2;
  const int ssw0 = (scol ^ ((srow >> 1) & 3)) * 8;
  const int ssw1 = ((scol + 1) ^ ((srow >> 1) & 3)) * 8;

  // fragment read: row = lane&15 within 16-row frag, k-chunk = lane>>4
  const int frow = lane & 15;
  const int fsw = ((lane >> 4) ^ ((frow >> 1) & 3)) * 8;  // swizzled chunk (loop-invariant)

  const bf16* Ap = A + (size_t)(tm + srow) * K + scol * 8;
  const bf16* Bp = Bm + (size_t)(tn + srow) * K + scol * 8;

  f32x4 acc[4][4] = {};

  for (int k0 = 0; k0 < K; k0 += 32) {
    uint4 a0 = *(const uint4*)Ap;
    uint4 a1 = *(const uint4*)(Ap + 8);
    uint4 b0 = *(const uint4*)Bp;
    uint4 b1 = *(const uint4*)(Bp + 8);
    Ap += 32;
    Bp += 32;
    __syncthreads();
    *(uint4*)(As + srow * 32 + ssw0) = a0;
    *(uint4*)(As + srow * 32 + ssw1) = a1;
    *(uint4*)(Bs + srow * 32 + ssw0) = b0;
    *(uint4*)(Bs + srow * 32 + ssw1) = b1;
    __syncthreads();
    bf16x8 af[4], bfr[4];
#pragma unroll
    for (int i = 0; i < 4; i++) {
      af[i] = *(const bf16x8*)(As + (wm + i * 16 + frow) * 32 + fsw);
      bfr[i] = *(const bf16x8*)(Bs + (wn + i * 16 + frow) * 32 + fsw);
    }
#pragma unroll
    for (int i = 0; i < 4; i++)
#pragma unroll
      for (int j = 0; j < 4; j++)
        acc[i][j] = __builtin_amdgcn_mfma_f32_16x16x32_bf16(af[i], bfr[j], acc[i][j], 0, 0, 0);
  }

  // epilogue: C/D layout col = lane&15, row = (lane>>4)*4 + r
  const int crow0 = tm + wm + (lane >> 4) * 4;
  const int ccol0 = tn + wn + (lane & 15);
  if (MODE == 0) {
    bf16* Cq = (bf16*)Cout;
#pragma unroll
    for (int i = 0; i < 4; i++) {
#pragma unroll
      for (int j = 0; j < 4; j++) {
        const int col = ccol0 + j * 16;
        const bool isqk = (col < 2 * C_);
#pragma unroll
        for (int r = 0; r < 4; r++) {
          const int row = crow0 + i * 16 + r;
          float v = acc[i][j][r];
          if (isqk) v = (v > 0.f) ? (v + 1.0f) : __expf(v);
          Cq[(size_t)row * N + col] = (bf16)v;
        }
      }
    }
  } else {
    float* Cf = (float*)Cout;
#pragma unroll
    for (int i = 0; i < 4; i++) {
#pragma unroll
      for (int j = 0; j < 4; j++) {
        const int col = ccol0 + j * 16;
        const float bv = bias[col];
#pragma unroll
        for (int r = 0; r < 4; r++) {
          const int row = crow0 + i * 16 + r;
          Cf[(size_t)row * N + col] = acc[i][j][r] + bv;
        }
      }
    }
  }
}

// ---------------- kv partial: kv[b,h,d,m] = sum_n k[b,n,h,d]*v[b,n,h,m] ----------------
__global__ __launch_bounds__(256) void kv_kernel(const bf16* __restrict__ qkv, float* __restrict__ partial) {
  const int bh = blockIdx.x & 63;
  const int ch = blockIdx.x >> 6;
  const int b = bh >> 4;
  const int h = bh & 15;
  const int tid = threadIdx.x;
  const int d = tid & 63;
  const int mb = tid >> 6;

  __shared__ float kb[8][64];
  __shared__ float vb[8][64];

  float acc[16] = {};
  float ks = 0.f;

  const int Tc = T_ / NCH;  // 256
  const int n0 = ch * Tc;

  for (int nb = 0; nb < Tc; nb += 8) {
    __syncthreads();
#pragma unroll
    for (int i = 0; i < 4; i++) {
      int q = tid * 4 + i;
      int nn = q >> 7;
      int r = q & 127;
      const bf16* rowp = qkv + (size_t)(b * T_ + n0 + nb + nn) * 3072 + C_ + h * 64;
      float val = (float)rowp[(r < 64) ? r : (C_ + r - 64)];
      if (r < 64) kb[nn][r] = val;
      else vb[nn][r - 64] = val;
    }
    __syncthreads();
#pragma unroll
    for (int nn = 0; nn < 8; nn++) {
      float kd = kb[nn][d];
      if (mb == 0) ks += kd;
#pragma unroll
      for (int j = 0; j < 16; j++)
        acc[j] += kd * vb[nn][mb * 16 + j];
    }
  }

  float* p = partial + (size_t)(ch * 64 + bh) * 4160;
#pragma unroll
  for (int j = 0; j < 16; j++)
    p[d * 64 + mb * 16 + j] = acc[j];
  if (mb == 0) p[4096 + d] = ks;
}

__global__ void kv_reduce(const float* __restrict__ partial, float* __restrict__ kvout) {
  int i = blockIdx.x * blockDim.x + threadIdx.x;
  if (i >= 64 * 4160) return;
  int bh = i / 4160;
  int j = i % 4160;
  float s = 0.f;
#pragma unroll
  for (int ch = 0; ch < NCH; ch++)
    s += partial[(size_t)(ch * 64 + bh) * 4160 + j];
  kvout[i] = s;
}

// ---------------- attn out: out[b,t,h,m] = (q . kv[:,m]) / (q . ksum + eps) ----------------
__global__ __launch_bounds__(256) void attn_kernel(const bf16* __restrict__ qkv,
                                                   const float* __restrict__ kv,
                                                   bf16* __restrict__ attn) {
  const int bh = blockIdx.x >> 5;
  const int tch = blockIdx.x & 31;
  const int b = bh >> 4;
  const int h = bh & 15;

  __shared__ float kvs[4096];
  __shared__ float kss[64];

  const float* kvp = kv + (size_t)bh * 4160;
  for (int i = threadIdx.x; i < 4096; i += 256) kvs[i] = kvp[i];
  if (threadIdx.x < 64) kss[threadIdx.x] = kvp[4096 + threadIdx.x];
  __syncthreads();

  const int lane = threadIdx.x & 63;
  const int wave = threadIdx.x >> 6;

  for (int t = tch * 128 + wave; t < (tch + 1) * 128; t += 4) {
    const size_t base = (size_t)(b * T_ + t) * 3072 + h * 64;
    float qv = (float)qkv[base + lane];
    float nrm = qv * kss[lane];
#pragma unroll
    for (int off = 32; off; off >>= 1) nrm += __shfl_xor(nrm, off);
    nrm += EPS_;
    float acc = 0.f;
#pragma unroll
    for (int dd = 0; dd < 64; dd++) {
      float qd = __shfl(qv, dd);
      acc += qd * kvs[dd * 64 + lane];
    }
    attn[(size_t)(b * T_ + t) * 1024 + h * 64 + lane] = (bf16)(acc / nrm);
  }
}

// ---------------- launch ----------------
extern "C" void kernel_launch(void* const* d_in, const int* in_sizes, int n_in,
                              void* d_out, int out_size, void* d_ws, size_t ws_size,
                              hipStream_t stream) {
  const float* x = (const float*)d_in[0];
  const float* Wqkv = (const float*)d_in[1];
  const float* Wproj = (const float*)d_in[2];
  const float* bproj = (const float*)d_in[3];
  float* out = (float*)d_out;

  char* w = (char*)d_ws;
  bf16* xw = (bf16*)w;      w += (size_t)16777216 * 2;   // x bf16
  bf16* wqkv = (bf16*)w;    w += (size_t)3145728 * 2;    // Wqkv bf16
  bf16* wproj = (bf16*)w;   w += (size_t)1048576 * 2;    // Wproj bf16
  bf16* qkv = (bf16*)w;     w += (size_t)50331648 * 2;   // qkv (phi applied to q,k) bf16
  bf16* attn = (bf16*)w;    w += (size_t)16777216 * 2;   // normalized attn out bf16
  float* partial = (float*)w; w += (size_t)NCH * 64 * 4160 * 4;
  float* kvf = (float*)w;   // 64*4160 f32

  cast_kernel<<<8192, 256, 0, stream>>>(x, xw, 16777216 / 8);
  cast_kernel<<<1536, 256, 0, stream>>>(Wqkv, wqkv, 3145728 / 8);
  cast_kernel<<<512, 256, 0, stream>>>(Wproj, wproj, 1048576 / 8);

  // qkv = x @ Wqkv^T, phi fused on q,k
  gemm_nt<0><<<128 * 24, 256, 0, stream>>>(xw, wqkv, (void*)qkv, nullptr, 16384, 3072, 1024, 24);

  kv_kernel<<<NCH * 64, 256, 0, stream>>>(qkv, partial);
  kv_reduce<<<(64 * 4160 + 255) / 256, 256, 0, stream>>>(partial, kvf);

  attn_kernel<<<64 * 32, 256, 0, stream>>>(qkv, kvf, attn);

  // out = attn @ Wproj^T + bproj
  gemm_nt<1><<<128 * 8, 256, 0, stream>>>(attn, wproj, (void*)out, bproj, 16384, 1024, 1024, 8);
}

// Round 2
// 350.962 us; speedup vs baseline: 1.4386x; 1.4386x over previous
//
#include <hip/hip_runtime.h>

typedef __bf16 bf16;
typedef bf16 bf16x8 __attribute__((ext_vector_type(8)));
typedef float f32x4 __attribute__((ext_vector_type(4)));

#define B_ 4
#define T_ 4096
#define C_ 1024
#define H_ 16
#define D_ 64
#define NCH 16
#define EPS_ 1e-6f

// ---------------- cast f32 -> bf16 (vectorized, 8/thread) ----------------
__global__ void cast_kernel(const float* __restrict__ in, bf16* __restrict__ out, int n8) {
  int i = blockIdx.x * blockDim.x + threadIdx.x;
  int stride = gridDim.x * blockDim.x;
  for (; i < n8; i += stride) {
    const float4* p = (const float4*)(in + (size_t)i * 8);
    float4 v0 = p[0];
    float4 v1 = p[1];
    bf16x8 o;
    o[0] = (bf16)v0.x; o[1] = (bf16)v0.y; o[2] = (bf16)v0.z; o[3] = (bf16)v0.w;
    o[4] = (bf16)v1.x; o[5] = (bf16)v1.y; o[6] = (bf16)v1.z; o[7] = (bf16)v1.w;
    *(bf16x8*)(out + (size_t)i * 8) = o;
  }
}

// ---------------- NT GEMM: C[M][N] = A[M][K] * B[N][K]^T ----------------
template <int MODE>
__global__ __launch_bounds__(256) void gemm_nt(
    const bf16* __restrict__ A, const bf16* __restrict__ Bm,
    void* __restrict__ Cout, const float* __restrict__ bias,
    int M, int N, int K, int tiles_n) {
  __shared__ bf16 As[128 * 32];
  __shared__ bf16 Bs[128 * 32];

  const int tid = threadIdx.x;
  const int lane = tid & 63;
  const int wave = tid >> 6;
  const int wm = (wave >> 1) * 64;
  const int wn = (wave & 1) * 64;

  const int tm = (blockIdx.x / tiles_n) * 128;
  const int tn = (blockIdx.x % tiles_n) * 128;

  const int srow = tid >> 1;
  const int scol = (tid & 1) * 2;
  const int ssw0 = (scol ^ ((srow >> 1) & 3)) * 8;
  const int ssw1 = ((scol + 1) ^ ((srow >> 1) & 3)) * 8;

  const int frow = lane & 15;
  const int fsw = ((lane >> 4) ^ ((frow >> 1) & 3)) * 8;

  const bf16* Ap = A + (size_t)(tm + srow) * K + scol * 8;
  const bf16* Bp = Bm + (size_t)(tn + srow) * K + scol * 8;

  f32x4 acc[4][4] = {};

  for (int k0 = 0; k0 < K; k0 += 32) {
    uint4 a0 = *(const uint4*)Ap;
    uint4 a1 = *(const uint4*)(Ap + 8);
    uint4 b0 = *(const uint4*)Bp;
    uint4 b1 = *(const uint4*)(Bp + 8);
    Ap += 32;
    Bp += 32;
    __syncthreads();
    *(uint4*)(As + srow * 32 + ssw0) = a0;
    *(uint4*)(As + srow * 32 + ssw1) = a1;
    *(uint4*)(Bs + srow * 32 + ssw0) = b0;
    *(uint4*)(Bs + srow * 32 + ssw1) = b1;
    __syncthreads();
    bf16x8 af[4], bfr[4];
#pragma unroll
    for (int i = 0; i < 4; i++) {
      af[i] = *(const bf16x8*)(As + (wm + i * 16 + frow) * 32 + fsw);
      bfr[i] = *(const bf16x8*)(Bs + (wn + i * 16 + frow) * 32 + fsw);
    }
#pragma unroll
    for (int i = 0; i < 4; i++)
#pragma unroll
      for (int j = 0; j < 4; j++)
        acc[i][j] = __builtin_amdgcn_mfma_f32_16x16x32_bf16(af[i], bfr[j], acc[i][j], 0, 0, 0);
  }

  const int crow0 = tm + wm + (lane >> 4) * 4;
  const int ccol0 = tn + wn + (lane & 15);
  if (MODE == 0) {
    bf16* Cq = (bf16*)Cout;
#pragma unroll
    for (int i = 0; i < 4; i++) {
#pragma unroll
      for (int j = 0; j < 4; j++) {
        const int col = ccol0 + j * 16;
        const bool isqk = (col < 2 * C_);
#pragma unroll
        for (int r = 0; r < 4; r++) {
          const int row = crow0 + i * 16 + r;
          float v = acc[i][j][r];
          if (isqk) v = (v > 0.f) ? (v + 1.0f) : __expf(v);
          Cq[(size_t)row * N + col] = (bf16)v;
        }
      }
    }
  } else {
    float* Cf = (float*)Cout;
#pragma unroll
    for (int i = 0; i < 4; i++) {
#pragma unroll
      for (int j = 0; j < 4; j++) {
        const int col = ccol0 + j * 16;
        const float bv = bias[col];
#pragma unroll
        for (int r = 0; r < 4; r++) {
          const int row = crow0 + i * 16 + r;
          Cf[(size_t)row * N + col] = acc[i][j][r] + bv;
        }
      }
    }
  }
}

// ---------------- kv partial: kv[b,h,d,m] = sum_n k[b,n,h,d]*v[b,n,h,m] ----------------
__global__ __launch_bounds__(256) void kv_kernel(const bf16* __restrict__ qkv, float* __restrict__ partial) {
  const int bh = blockIdx.x & 63;
  const int ch = blockIdx.x >> 6;
  const int b = bh >> 4;
  const int h = bh & 15;
  const int tid = threadIdx.x;
  const int d = tid & 63;
  const int mb = tid >> 6;

  __shared__ float kb[8][64];
  __shared__ float vb[8][64];

  float acc[16] = {};
  float ks = 0.f;

  const int Tc = T_ / NCH;  // 256
  const int n0 = ch * Tc;

  for (int nb = 0; nb < Tc; nb += 8) {
    __syncthreads();
#pragma unroll
    for (int i = 0; i < 4; i++) {
      int q = tid * 4 + i;
      int nn = q >> 7;
      int r = q & 127;
      const bf16* rowp = qkv + (size_t)(b * T_ + n0 + nb + nn) * 3072 + C_ + h * 64;
      float val = (float)rowp[(r < 64) ? r : (C_ + r - 64)];
      if (r < 64) kb[nn][r] = val;
      else vb[nn][r - 64] = val;
    }
    __syncthreads();
#pragma unroll
    for (int nn = 0; nn < 8; nn++) {
      float kd = kb[nn][d];
      if (mb == 0) ks += kd;
#pragma unroll
      for (int j = 0; j < 16; j++)
        acc[j] += kd * vb[nn][mb * 16 + j];
    }
  }

  float* p = partial + (size_t)(ch * 64 + bh) * 4160;
#pragma unroll
  for (int j = 0; j < 16; j++)
    p[d * 64 + mb * 16 + j] = acc[j];
  if (mb == 0) p[4096 + d] = ks;
}

// ---------------- reduce partials -> kvb bf16 [bh][80][64] ----------------
// rows 0..63: kvT[m][d] = kv[d][m]; row 64: ksum_hi[d]; row 65: ksum_lo[d]; rows 66..79: 0
__global__ void kv_reduce_b(const float* __restrict__ partial, bf16* __restrict__ kvb) {
  int i = blockIdx.x * blockDim.x + threadIdx.x;
  if (i >= 64 * 80 * 64) return;
  int d = i & 63;
  int row = (i >> 6) % 80;
  int bh = i / (80 * 64);
  float outv = 0.f;
  if (row < 64) {
    float s = 0.f;
#pragma unroll
    for (int ch = 0; ch < NCH; ch++)
      s += partial[(size_t)(ch * 64 + bh) * 4160 + d * 64 + row];
    outv = s;
    kvb[(size_t)bh * 5120 + row * 64 + d] = (bf16)outv;
    return;
  } else if (row < 66) {
    float ks = 0.f;
#pragma unroll
    for (int ch = 0; ch < NCH; ch++)
      ks += partial[(size_t)(ch * 64 + bh) * 4160 + 4096 + d];
    bf16 hi = (bf16)ks;
    outv = (row == 64) ? (float)hi : (ks - (float)hi);
  }
  kvb[(size_t)bh * 5120 + row * 64 + d] = (bf16)outv;
}

// ---------------- attn out via MFMA: out[t,m] = (q[t,:].kvT[m,:]) / (q.ksum + eps) -----
__global__ __launch_bounds__(256) void attn_mfma(const bf16* __restrict__ qkv,
                                                 const bf16* __restrict__ kvb,
                                                 bf16* __restrict__ attn) {
  const int bh = blockIdx.x >> 4;
  const int tch = blockIdx.x & 15;
  const int b = bh >> 4;
  const int h = bh & 15;
  const int lane = threadIdx.x & 63;
  const int wave = threadIdx.x >> 6;
  const int t0 = tch * 256 + wave * 64;

  // B-frags (loop-invariant): 5 col-tiles x 2 k-halves
  const bf16* kvp = kvb + (size_t)bh * 5120;
  bf16x8 bfrag[5][2];
#pragma unroll
  for (int j = 0; j < 5; j++)
#pragma unroll
    for (int kk = 0; kk < 2; kk++)
      bfrag[j][kk] = *(const bf16x8*)(kvp + (j * 16 + (lane & 15)) * 64 + kk * 32 + (lane >> 4) * 8);

  f32x4 acc[4][5] = {};
#pragma unroll
  for (int i = 0; i < 4; i++) {
    const int t = t0 + i * 16 + (lane & 15);
    const bf16* qp = qkv + (size_t)(b * T_ + t) * 3072 + h * 64 + (lane >> 4) * 8;
    bf16x8 a0 = *(const bf16x8*)qp;
    bf16x8 a1 = *(const bf16x8*)(qp + 32);
#pragma unroll
    for (int j = 0; j < 5; j++) {
      acc[i][j] = __builtin_amdgcn_mfma_f32_16x16x32_bf16(a0, bfrag[j][0], acc[i][j], 0, 0, 0);
      acc[i][j] = __builtin_amdgcn_mfma_f32_16x16x32_bf16(a1, bfrag[j][1], acc[i][j], 0, 0, 0);
    }
  }

  // epilogue: C/D layout col = lane&15, row = (lane>>4)*4 + r
#pragma unroll
  for (int i = 0; i < 4; i++) {
#pragma unroll
    for (int r = 0; r < 4; r++) {
      float hi = __shfl(acc[i][4][r], (lane & 48));
      float lo = __shfl(acc[i][4][r], (lane & 48) + 1);
      float inv = 1.0f / (hi + lo + EPS_);
      const int t = t0 + i * 16 + (lane >> 4) * 4 + r;
      bf16* op = attn + (size_t)(b * T_ + t) * 1024 + h * 64 + (lane & 15);
#pragma unroll
      for (int j = 0; j < 4; j++)
        op[j * 16] = (bf16)(acc[i][j][r] * inv);
    }
  }
}

// ---------------- launch ----------------
extern "C" void kernel_launch(void* const* d_in, const int* in_sizes, int n_in,
                              void* d_out, int out_size, void* d_ws, size_t ws_size,
                              hipStream_t stream) {
  const float* x = (const float*)d_in[0];
  const float* Wqkv = (const float*)d_in[1];
  const float* Wproj = (const float*)d_in[2];
  const float* bproj = (const float*)d_in[3];
  float* out = (float*)d_out;

  char* w = (char*)d_ws;
  bf16* xw = (bf16*)w;      w += (size_t)16777216 * 2;   // x bf16
  bf16* wqkv = (bf16*)w;    w += (size_t)3145728 * 2;    // Wqkv bf16
  bf16* wproj = (bf16*)w;   w += (size_t)1048576 * 2;    // Wproj bf16
  bf16* qkv = (bf16*)w;     w += (size_t)50331648 * 2;   // qkv (phi applied to q,k) bf16
  bf16* attn = (bf16*)w;    w += (size_t)16777216 * 2;   // normalized attn out bf16
  float* partial = (float*)w; w += (size_t)NCH * 64 * 4160 * 4;
  bf16* kvb = (bf16*)w;     // 64*80*64 bf16

  cast_kernel<<<8192, 256, 0, stream>>>(x, xw, 16777216 / 8);
  cast_kernel<<<1536, 256, 0, stream>>>(Wqkv, wqkv, 3145728 / 8);
  cast_kernel<<<512, 256, 0, stream>>>(Wproj, wproj, 1048576 / 8);

  // qkv = x @ Wqkv^T, phi fused on q,k
  gemm_nt<0><<<128 * 24, 256, 0, stream>>>(xw, wqkv, (void*)qkv, nullptr, 16384, 3072, 1024, 24);

  kv_kernel<<<NCH * 64, 256, 0, stream>>>(qkv, partial);
  kv_reduce_b<<<(64 * 80 * 64 + 255) / 256, 256, 0, stream>>>(partial, kvb);

  attn_mfma<<<64 * 16, 256, 0, stream>>>(qkv, kvb, attn);

  // out = attn @ Wproj^T + bproj
  gemm_nt<1><<<128 * 8, 256, 0, stream>>>(attn, wproj, (void*)out, bproj, 16384, 1024, 1024, 8);
}

// Round 3
// 339.818 us; speedup vs baseline: 1.4857x; 1.0328x over previous
//
#include <hip/hip_runtime.h>

typedef __bf16 bf16;
typedef bf16 bf16x8 __attribute__((ext_vector_type(8)));
typedef float f32x4 __attribute__((ext_vector_type(4)));

#define B_ 4
#define T_ 4096
#define C_ 1024
#define H_ 16
#define D_ 64
#define NCH 16
#define EPS_ 1e-6f

typedef __attribute__((address_space(1))) const void* as1p;
typedef __attribute__((address_space(3))) void* as3p;

// ---------------- cast f32 -> bf16 (vectorized, 8/thread) ----------------
__global__ void cast_kernel(const float* __restrict__ in, bf16* __restrict__ out, int n8) {
  int i = blockIdx.x * blockDim.x + threadIdx.x;
  int stride = gridDim.x * blockDim.x;
  for (; i < n8; i += stride) {
    const float4* p = (const float4*)(in + (size_t)i * 8);
    float4 v0 = p[0];
    float4 v1 = p[1];
    bf16x8 o;
    o[0] = (bf16)v0.x; o[1] = (bf16)v0.y; o[2] = (bf16)v0.z; o[3] = (bf16)v0.w;
    o[4] = (bf16)v1.x; o[5] = (bf16)v1.y; o[6] = (bf16)v1.z; o[7] = (bf16)v1.w;
    *(bf16x8*)(out + (size_t)i * 8) = o;
  }
}

// ---------------- NT GEMM: C[M][N] = A[M][K] * B[N][K]^T ----------------
// Staging via global_load_lds(16B): linear LDS dest + inverse-XOR-swizzled
// global source; fragment ds_read_b128 applies the same XOR -> conflict-free.
template <int MODE>
__global__ __launch_bounds__(256) void gemm_nt(
    const bf16* __restrict__ A, const bf16* __restrict__ Bm,
    void* __restrict__ Cout, const float* __restrict__ bias,
    int M, int N, int K, int tiles_n) {
  __shared__ bf16 As[128 * 32];
  __shared__ bf16 Bs[128 * 32];

  const int tid = threadIdx.x;
  const int lane = tid & 63;
  const int wave = tid >> 6;
  const int wm = (wave >> 1) * 64;
  const int wn = (wave & 1) * 64;

  const int tm = (blockIdx.x / tiles_n) * 128;
  const int tn = (blockIdx.x % tiles_n) * 128;

  // ---- staging geometry: group g = wave*2+c covers rows g*16..g*16+15 ----
  // lane i -> row g*16 + (i>>2), LDS slot (i&3); global chunk cc = slot ^ ((row>>1)&3)
  const int r0 = (wave * 2 + 0) * 16 + (lane >> 2);
  const int r1 = (wave * 2 + 1) * 16 + (lane >> 2);
  const int cc0 = (lane & 3) ^ ((r0 >> 1) & 3);
  const int cc1 = (lane & 3) ^ ((r1 >> 1) & 3);

  const bf16* gA0 = A + (size_t)(tm + r0) * K + cc0 * 8;
  const bf16* gA1 = A + (size_t)(tm + r1) * K + cc1 * 8;
  const bf16* gB0 = Bm + (size_t)(tn + r0) * K + cc0 * 8;
  const bf16* gB1 = Bm + (size_t)(tn + r1) * K + cc1 * 8;

  bf16* lA0 = As + (wave * 2 + 0) * 512;
  bf16* lA1 = As + (wave * 2 + 1) * 512;
  bf16* lB0 = Bs + (wave * 2 + 0) * 512;
  bf16* lB1 = Bs + (wave * 2 + 1) * 512;

  // ---- fragment read: row = lane&15 within frag, swizzled k-chunk ----
  const int frow = lane & 15;
  const int fsw = ((lane >> 4) ^ ((frow >> 1) & 3)) * 8;

  f32x4 acc[4][4] = {};

  for (int k0 = 0; k0 < K; k0 += 32) {
    __syncthreads();  // all waves done reading LDS from previous step
    __builtin_amdgcn_global_load_lds((as1p)(gA0 + k0), (as3p)lA0, 16, 0, 0);
    __builtin_amdgcn_global_load_lds((as1p)(gA1 + k0), (as3p)lA1, 16, 0, 0);
    __builtin_amdgcn_global_load_lds((as1p)(gB0 + k0), (as3p)lB0, 16, 0, 0);
    __builtin_amdgcn_global_load_lds((as1p)(gB1 + k0), (as3p)lB1, 16, 0, 0);
    __syncthreads();  // barrier drain (vmcnt) makes staged data visible
    bf16x8 af[4], bfr[4];
#pragma unroll
    for (int i = 0; i < 4; i++) {
      af[i] = *(const bf16x8*)(As + (wm + i * 16 + frow) * 32 + fsw);
      bfr[i] = *(const bf16x8*)(Bs + (wn + i * 16 + frow) * 32 + fsw);
    }
#pragma unroll
    for (int i = 0; i < 4; i++)
#pragma unroll
      for (int j = 0; j < 4; j++)
        acc[i][j] = __builtin_amdgcn_mfma_f32_16x16x32_bf16(af[i], bfr[j], acc[i][j], 0, 0, 0);
  }

  // epilogue: C/D layout col = lane&15, row = (lane>>4)*4 + r
  const int crow0 = tm + wm + (lane >> 4) * 4;
  const int ccol0 = tn + wn + (lane & 15);
  if (MODE == 0) {
    bf16* Cq = (bf16*)Cout;
#pragma unroll
    for (int i = 0; i < 4; i++) {
#pragma unroll
      for (int j = 0; j < 4; j++) {
        const int col = ccol0 + j * 16;
        const bool isqk = (col < 2 * C_);
#pragma unroll
        for (int r = 0; r < 4; r++) {
          const int row = crow0 + i * 16 + r;
          float v = acc[i][j][r];
          if (isqk) v = (v > 0.f) ? (v + 1.0f) : __expf(v);
          Cq[(size_t)row * N + col] = (bf16)v;
        }
      }
    }
  } else {
    float* Cf = (float*)Cout;
#pragma unroll
    for (int i = 0; i < 4; i++) {
#pragma unroll
      for (int j = 0; j < 4; j++) {
        const int col = ccol0 + j * 16;
        const float bv = bias[col];
#pragma unroll
        for (int r = 0; r < 4; r++) {
          const int row = crow0 + i * 16 + r;
          Cf[(size_t)row * N + col] = acc[i][j][r] + bv;
        }
      }
    }
  }
}

// ---------------- kv partial: kv[b,h,d,m] = sum_n k[b,n,h,d]*v[b,n,h,m] ----------------
__global__ __launch_bounds__(256) void kv_kernel(const bf16* __restrict__ qkv, float* __restrict__ partial) {
  const int bh = blockIdx.x & 63;
  const int ch = blockIdx.x >> 6;
  const int b = bh >> 4;
  const int h = bh & 15;
  const int tid = threadIdx.x;
  const int d = tid & 63;
  const int mb = tid >> 6;

  __shared__ float kb[8][64];
  __shared__ float vb[8][64];

  float acc[16] = {};
  float ks = 0.f;

  const int Tc = T_ / NCH;  // 256
  const int n0 = ch * Tc;

  for (int nb = 0; nb < Tc; nb += 8) {
    __syncthreads();
#pragma unroll
    for (int i = 0; i < 4; i++) {
      int q = tid * 4 + i;
      int nn = q >> 7;
      int r = q & 127;
      const bf16* rowp = qkv + (size_t)(b * T_ + n0 + nb + nn) * 3072 + C_ + h * 64;
      float val = (float)rowp[(r < 64) ? r : (C_ + r - 64)];
      if (r < 64) kb[nn][r] = val;
      else vb[nn][r - 64] = val;
    }
    __syncthreads();
#pragma unroll
    for (int nn = 0; nn < 8; nn++) {
      float kd = kb[nn][d];
      if (mb == 0) ks += kd;
#pragma unroll
      for (int j = 0; j < 16; j++)
        acc[j] += kd * vb[nn][mb * 16 + j];
    }
  }

  float* p = partial + (size_t)(ch * 64 + bh) * 4160;
#pragma unroll
  for (int j = 0; j < 16; j++)
    p[d * 64 + mb * 16 + j] = acc[j];
  if (mb == 0) p[4096 + d] = ks;
}

// ---------------- reduce partials -> kvb bf16 [bh][80][64] ----------------
// rows 0..63: kvT[m][d] = kv[d][m]; row 64: ksum_hi[d]; row 65: ksum_lo[d]; rows 66..79: 0
__global__ void kv_reduce_b(const float* __restrict__ partial, bf16* __restrict__ kvb) {
  int i = blockIdx.x * blockDim.x + threadIdx.x;
  if (i >= 64 * 80 * 64) return;
  int d = i & 63;
  int row = (i >> 6) % 80;
  int bh = i / (80 * 64);
  float outv = 0.f;
  if (row < 64) {
    float s = 0.f;
#pragma unroll
    for (int ch = 0; ch < NCH; ch++)
      s += partial[(size_t)(ch * 64 + bh) * 4160 + d * 64 + row];
    outv = s;
    kvb[(size_t)bh * 5120 + row * 64 + d] = (bf16)outv;
    return;
  } else if (row < 66) {
    float ks = 0.f;
#pragma unroll
    for (int ch = 0; ch < NCH; ch++)
      ks += partial[(size_t)(ch * 64 + bh) * 4160 + 4096 + d];
    bf16 hi = (bf16)ks;
    outv = (row == 64) ? (float)hi : (ks - (float)hi);
  }
  kvb[(size_t)bh * 5120 + row * 64 + d] = (bf16)outv;
}

// ---------------- attn out via MFMA: out[t,m] = (q[t,:].kvT[m,:]) / (q.ksum + eps) -----
__global__ __launch_bounds__(256) void attn_mfma(const bf16* __restrict__ qkv,
                                                 const bf16* __restrict__ kvb,
                                                 bf16* __restrict__ attn) {
  const int bh = blockIdx.x >> 4;
  const int tch = blockIdx.x & 15;
  const int b = bh >> 4;
  const int h = bh & 15;
  const int lane = threadIdx.x & 63;
  const int wave = threadIdx.x >> 6;
  const int t0 = tch * 256 + wave * 64;

  const bf16* kvp = kvb + (size_t)bh * 5120;
  bf16x8 bfrag[5][2];
#pragma unroll
  for (int j = 0; j < 5; j++)
#pragma unroll
    for (int kk = 0; kk < 2; kk++)
      bfrag[j][kk] = *(const bf16x8*)(kvp + (j * 16 + (lane & 15)) * 64 + kk * 32 + (lane >> 4) * 8);

  f32x4 acc[4][5] = {};
#pragma unroll
  for (int i = 0; i < 4; i++) {
    const int t = t0 + i * 16 + (lane & 15);
    const bf16* qp = qkv + (size_t)(b * T_ + t) * 3072 + h * 64 + (lane >> 4) * 8;
    bf16x8 a0 = *(const bf16x8*)qp;
    bf16x8 a1 = *(const bf16x8*)(qp + 32);
#pragma unroll
    for (int j = 0; j < 5; j++) {
      acc[i][j] = __builtin_amdgcn_mfma_f32_16x16x32_bf16(a0, bfrag[j][0], acc[i][j], 0, 0, 0);
      acc[i][j] = __builtin_amdgcn_mfma_f32_16x16x32_bf16(a1, bfrag[j][1], acc[i][j], 0, 0, 0);
    }
  }

#pragma unroll
  for (int i = 0; i < 4; i++) {
#pragma unroll
    for (int r = 0; r < 4; r++) {
      float hi = __shfl(acc[i][4][r], (lane & 48));
      float lo = __shfl(acc[i][4][r], (lane & 48) + 1);
      float inv = 1.0f / (hi + lo + EPS_);
      const int t = t0 + i * 16 + (lane >> 4) * 4 + r;
      bf16* op = attn + (size_t)(b * T_ + t) * 1024 + h * 64 + (lane & 15);
#pragma unroll
      for (int j = 0; j < 4; j++)
        op[j * 16] = (bf16)(acc[i][j][r] * inv);
    }
  }
}

// ---------------- launch ----------------
extern "C" void kernel_launch(void* const* d_in, const int* in_sizes, int n_in,
                              void* d_out, int out_size, void* d_ws, size_t ws_size,
                              hipStream_t stream) {
  const float* x = (const float*)d_in[0];
  const float* Wqkv = (const float*)d_in[1];
  const float* Wproj = (const float*)d_in[2];
  const float* bproj = (const float*)d_in[3];
  float* out = (float*)d_out;

  char* w = (char*)d_ws;
  bf16* xw = (bf16*)w;      w += (size_t)16777216 * 2;   // x bf16
  bf16* wqkv = (bf16*)w;    w += (size_t)3145728 * 2;    // Wqkv bf16
  bf16* wproj = (bf16*)w;   w += (size_t)1048576 * 2;    // Wproj bf16
  bf16* qkv = (bf16*)w;     w += (size_t)50331648 * 2;   // qkv (phi applied to q,k) bf16
  bf16* attn = (bf16*)w;    w += (size_t)16777216 * 2;   // normalized attn out bf16
  float* partial = (float*)w; w += (size_t)NCH * 64 * 4160 * 4;
  bf16* kvb = (bf16*)w;     // 64*80*64 bf16

  cast_kernel<<<8192, 256, 0, stream>>>(x, xw, 16777216 / 8);
  cast_kernel<<<1536, 256, 0, stream>>>(Wqkv, wqkv, 3145728 / 8);
  cast_kernel<<<512, 256, 0, stream>>>(Wproj, wproj, 1048576 / 8);

  // qkv = x @ Wqkv^T, phi fused on q,k
  gemm_nt<0><<<128 * 24, 256, 0, stream>>>(xw, wqkv, (void*)qkv, nullptr, 16384, 3072, 1024, 24);

  kv_kernel<<<NCH * 64, 256, 0, stream>>>(qkv, partial);
  kv_reduce_b<<<(64 * 80 * 64 + 255) / 256, 256, 0, stream>>>(partial, kvb);

  attn_mfma<<<64 * 16, 256, 0, stream>>>(qkv, kvb, attn);

  // out = attn @ Wproj^T + bproj
  gemm_nt<1><<<128 * 8, 256, 0, stream>>>(attn, wproj, (void*)out, bproj, 16384, 1024, 1024, 8);
}

// Round 4
// 301.261 us; speedup vs baseline: 1.6759x; 1.1280x over previous
//
#include <hip/hip_runtime.h>

typedef __bf16 bf16;
typedef bf16 bf16x8 __attribute__((ext_vector_type(8)));
typedef float f32x4 __attribute__((ext_vector_type(4)));

#define B_ 4
#define T_ 4096
#define C_ 1024
#define NCH 16
#define EPS_ 1e-6f

typedef __attribute__((address_space(1))) const void* as1p;
typedef __attribute__((address_space(3))) void* as3p;

// ---------------- cast f32 -> bf16 (vectorized, 8/thread) ----------------
__global__ void cast_kernel(const float* __restrict__ in, bf16* __restrict__ out, int n8) {
  int i = blockIdx.x * blockDim.x + threadIdx.x;
  int stride = gridDim.x * blockDim.x;
  for (; i < n8; i += stride) {
    const float4* p = (const float4*)(in + (size_t)i * 8);
    float4 v0 = p[0];
    float4 v1 = p[1];
    bf16x8 o;
    o[0] = (bf16)v0.x; o[1] = (bf16)v0.y; o[2] = (bf16)v0.z; o[3] = (bf16)v0.w;
    o[4] = (bf16)v1.x; o[5] = (bf16)v1.y; o[6] = (bf16)v1.z; o[7] = (bf16)v1.w;
    *(bf16x8*)(out + (size_t)i * 8) = o;
  }
}

// ---------------- pipelined NT GEMM: C[M][N] = A[M][K] * B[N][K]^T ----------------
// BM=256 BN=128 BK=64, 512 threads (8 waves, wave tile 64x64), triple-buffered LDS,
// 2-tile-ahead prefetch, counted vmcnt(6), 2 phases/K-tile, setprio around MFMA.
#define BM 256
#define BN 128
#define BK 64
#define ABYTES (BM * BK * 2)          // 32768
#define BBYTES (BN * BK * 2)          // 16384
#define BUFBYTES (ABYTES + BBYTES)    // 49152
#define SMEMBYTES (3 * BUFBYTES)      // 147456

template <int MODE>
__global__ __launch_bounds__(512, 1) void gemm3p(
    const bf16* __restrict__ A, const bf16* __restrict__ Bm,
    void* __restrict__ Cout, const float* __restrict__ bias,
    int M, int N, int K, int tiles_n) {
  extern __shared__ char smem[];
  const int tid = threadIdx.x;
  const int l = tid & 63;
  const int w = tid >> 6;
  const int wm = w >> 1;   // 0..3
  const int wn = w & 1;    // 0..1

  // T1: XCD-aware block swizzle (grid sizes are multiples of 8)
  const int cpx = gridDim.x >> 3;
  const int bid = (blockIdx.x & 7) * cpx + (blockIdx.x >> 3);
  const int tm = (bid / tiles_n) * BM;
  const int tn = (bid % tiles_n) * BN;

  // staging geometry: row within A/B tile = ld*64 + w*8 + (l>>3); slot = l&7
  // swizzle: content at (row, slot) = global chunk slot ^ (row&7); (ld*64)%8==0 so
  // g = (l&7) ^ ((l>>3)&7) is ld-invariant.
  const int srow = w * 8 + (l >> 3);
  const int g8 = (((l & 7) ^ ((l >> 3) & 7))) * 8;

  const bf16* srcA[4];
  const bf16* srcB[2];
#pragma unroll
  for (int ld = 0; ld < 4; ld++)
    srcA[ld] = A + (size_t)(tm + ld * 64 + srow) * K + g8;
#pragma unroll
  for (int ld = 0; ld < 2; ld++)
    srcB[ld] = Bm + (size_t)(tn + ld * 64 + srow) * K + g8;

  const int fr = l & 15;
  const int fc = l >> 4;
  const int NT = K >> 6;

  f32x4 acc[4][4] = {};

  // prologue: stage K-tiles 0 (buf0) and 1 (buf1)
#pragma unroll
  for (int kt = 0; kt < 2; kt++) {
#pragma unroll
    for (int ld = 0; ld < 4; ld++)
      __builtin_amdgcn_global_load_lds((as1p)(srcA[ld] + kt * BK),
          (as3p)(smem + kt * BUFBYTES + (ld * 8 + w) * 1024), 16, 0, 0);
#pragma unroll
    for (int ld = 0; ld < 2; ld++)
      __builtin_amdgcn_global_load_lds((as1p)(srcB[ld] + kt * BK),
          (as3p)(smem + kt * BUFBYTES + ABYTES + (ld * 8 + w) * 1024), 16, 0, 0);
  }
  asm volatile("s_waitcnt vmcnt(6)" ::: "memory");
  __builtin_amdgcn_s_barrier();
  __builtin_amdgcn_sched_barrier(0);

  int bufb = 0;
  for (int t = 0; t < NT; t++) {
    const bf16* Ab = (const bf16*)(smem + bufb);
    const bf16* Bb = (const bf16*)(smem + bufb + ABYTES);
    const bool pf = (t + 2 < NT);
    int pb = bufb + 2 * BUFBYTES;
    if (pb >= SMEMBYTES) pb -= SMEMBYTES;
    const int pko = (t + 2) * BK;

    // ---------- phase 0: B-frags(8) + A-frags mi0,1 (4); stage A0,A1,B0 ----------
    bf16x8 bfr[4][2], af[2][2];
#pragma unroll
    for (int nj = 0; nj < 4; nj++)
#pragma unroll
      for (int kk = 0; kk < 2; kk++) {
        const int row = wn * 64 + nj * 16 + fr;
        const int slot = (fc + 4 * kk) ^ (row & 7);
        bfr[nj][kk] = *(const bf16x8*)(Bb + row * 64 + slot * 8);
      }
#pragma unroll
    for (int mi = 0; mi < 2; mi++)
#pragma unroll
      for (int kk = 0; kk < 2; kk++) {
        const int row = wm * 64 + mi * 16 + fr;
        const int slot = (fc + 4 * kk) ^ (row & 7);
        af[mi][kk] = *(const bf16x8*)(Ab + row * 64 + slot * 8);
      }
    if (pf) {
      __builtin_amdgcn_global_load_lds((as1p)(srcA[0] + pko),
          (as3p)(smem + pb + (0 * 8 + w) * 1024), 16, 0, 0);
      __builtin_amdgcn_global_load_lds((as1p)(srcA[1] + pko),
          (as3p)(smem + pb + (1 * 8 + w) * 1024), 16, 0, 0);
      __builtin_amdgcn_global_load_lds((as1p)(srcB[0] + pko),
          (as3p)(smem + pb + ABYTES + (0 * 8 + w) * 1024), 16, 0, 0);
    }
    __builtin_amdgcn_s_barrier();
    __builtin_amdgcn_sched_barrier(0);
    __builtin_amdgcn_s_setprio(1);
#pragma unroll
    for (int mi = 0; mi < 2; mi++)
#pragma unroll
      for (int nj = 0; nj < 4; nj++)
#pragma unroll
        for (int kk = 0; kk < 2; kk++)
          acc[mi][nj] = __builtin_amdgcn_mfma_f32_16x16x32_bf16(af[mi][kk], bfr[nj][kk], acc[mi][nj], 0, 0, 0);
    __builtin_amdgcn_s_setprio(0);
    __builtin_amdgcn_s_barrier();
    __builtin_amdgcn_sched_barrier(0);

    // ---------- phase 1: A-frags mi2,3 (4); stage A2,A3,B1; end-of-tile gate ----------
#pragma unroll
    for (int mi = 0; mi < 2; mi++)
#pragma unroll
      for (int kk = 0; kk < 2; kk++) {
        const int row = wm * 64 + (mi + 2) * 16 + fr;
        const int slot = (fc + 4 * kk) ^ (row & 7);
        af[mi][kk] = *(const bf16x8*)(Ab + row * 64 + slot * 8);
      }
    if (pf) {
      __builtin_amdgcn_global_load_lds((as1p)(srcA[2] + pko),
          (as3p)(smem + pb + (2 * 8 + w) * 1024), 16, 0, 0);
      __builtin_amdgcn_global_load_lds((as1p)(srcA[3] + pko),
          (as3p)(smem + pb + (3 * 8 + w) * 1024), 16, 0, 0);
      __builtin_amdgcn_global_load_lds((as1p)(srcB[1] + pko),
          (as3p)(smem + pb + ABYTES + (1 * 8 + w) * 1024), 16, 0, 0);
    }
    __builtin_amdgcn_s_barrier();
    __builtin_amdgcn_sched_barrier(0);
    __builtin_amdgcn_s_setprio(1);
#pragma unroll
    for (int mi = 0; mi < 2; mi++)
#pragma unroll
      for (int nj = 0; nj < 4; nj++)
#pragma unroll
        for (int kk = 0; kk < 2; kk++)
          acc[mi + 2][nj] = __builtin_amdgcn_mfma_f32_16x16x32_bf16(af[mi][kk], bfr[nj][kk], acc[mi + 2][nj], 0, 0, 0);
    __builtin_amdgcn_s_setprio(0);
    // gate: all loads except the (up to) 6 newest (tile t+2's) have landed -> tile t+1 ready
    if (pf) asm volatile("s_waitcnt vmcnt(6)" ::: "memory");
    else    asm volatile("s_waitcnt vmcnt(0)" ::: "memory");
    __builtin_amdgcn_s_barrier();
    __builtin_amdgcn_sched_barrier(0);

    bufb += BUFBYTES;
    if (bufb >= SMEMBYTES) bufb = 0;
  }

  // ---------------- epilogue ----------------
  const int crow0 = tm + wm * 64 + (l >> 4) * 4;
  const int ccol0 = tn + wn * 64 + (l & 15);
  if (MODE == 0) {
    bf16* Cq = (bf16*)Cout;
#pragma unroll
    for (int mi = 0; mi < 4; mi++)
#pragma unroll
      for (int nj = 0; nj < 4; nj++) {
        const int col = ccol0 + nj * 16;
        const bool isqk = (col < 2 * C_);
#pragma unroll
        for (int r = 0; r < 4; r++) {
          const int row = crow0 + mi * 16 + r;
          float v = acc[mi][nj][r];
          if (isqk) v = (v > 0.f) ? (v + 1.0f) : __expf(v);
          Cq[(size_t)row * N + col] = (bf16)v;
        }
      }
  } else {
    float* Cf = (float*)Cout;
#pragma unroll
    for (int mi = 0; mi < 4; mi++)
#pragma unroll
      for (int nj = 0; nj < 4; nj++) {
        const int col = ccol0 + nj * 16;
        const float bv = bias[col];
#pragma unroll
        for (int r = 0; r < 4; r++) {
          const int row = crow0 + mi * 16 + r;
          Cf[(size_t)row * N + col] = acc[mi][nj][r] + bv;
        }
      }
  }
}

// ---------------- kv partial: kv[b,h,d,m] = sum_n k[b,n,h,d]*v[b,n,h,m] ----------------
__global__ __launch_bounds__(256) void kv_kernel(const bf16* __restrict__ qkv, float* __restrict__ partial) {
  const int bh = blockIdx.x & 63;
  const int ch = blockIdx.x >> 6;
  const int b = bh >> 4;
  const int h = bh & 15;
  const int tid = threadIdx.x;
  const int d = tid & 63;
  const int mb = tid >> 6;

  __shared__ float kb[8][64];
  __shared__ float vb[8][64];

  float acc[16] = {};
  float ks = 0.f;

  const int Tc = T_ / NCH;  // 256
  const int n0 = ch * Tc;

  for (int nb = 0; nb < Tc; nb += 8) {
    __syncthreads();
#pragma unroll
    for (int i = 0; i < 4; i++) {
      int q = tid * 4 + i;
      int nn = q >> 7;
      int r = q & 127;
      const bf16* rowp = qkv + (size_t)(b * T_ + n0 + nb + nn) * 3072 + C_ + h * 64;
      float val = (float)rowp[(r < 64) ? r : (C_ + r - 64)];
      if (r < 64) kb[nn][r] = val;
      else vb[nn][r - 64] = val;
    }
    __syncthreads();
#pragma unroll
    for (int nn = 0; nn < 8; nn++) {
      float kd = kb[nn][d];
      if (mb == 0) ks += kd;
#pragma unroll
      for (int j = 0; j < 16; j++)
        acc[j] += kd * vb[nn][mb * 16 + j];
    }
  }

  float* p = partial + (size_t)(ch * 64 + bh) * 4160;
#pragma unroll
  for (int j = 0; j < 16; j++)
    p[d * 64 + mb * 16 + j] = acc[j];
  if (mb == 0) p[4096 + d] = ks;
}

// ---------------- reduce partials -> kvb bf16 [bh][80][64] ----------------
__global__ void kv_reduce_b(const float* __restrict__ partial, bf16* __restrict__ kvb) {
  int i = blockIdx.x * blockDim.x + threadIdx.x;
  if (i >= 64 * 80 * 64) return;
  int d = i & 63;
  int row = (i >> 6) % 80;
  int bh = i / (80 * 64);
  float outv = 0.f;
  if (row < 64) {
    float s = 0.f;
#pragma unroll
    for (int ch = 0; ch < NCH; ch++)
      s += partial[(size_t)(ch * 64 + bh) * 4160 + d * 64 + row];
    kvb[(size_t)bh * 5120 + row * 64 + d] = (bf16)s;
    return;
  } else if (row < 66) {
    float ks = 0.f;
#pragma unroll
    for (int ch = 0; ch < NCH; ch++)
      ks += partial[(size_t)(ch * 64 + bh) * 4160 + 4096 + d];
    bf16 hi = (bf16)ks;
    outv = (row == 64) ? (float)hi : (ks - (float)hi);
  }
  kvb[(size_t)bh * 5120 + row * 64 + d] = (bf16)outv;
}

// ---------------- attn out via MFMA ----------------
__global__ __launch_bounds__(256) void attn_mfma(const bf16* __restrict__ qkv,
                                                 const bf16* __restrict__ kvb,
                                                 bf16* __restrict__ attn) {
  const int bh = blockIdx.x >> 4;
  const int tch = blockIdx.x & 15;
  const int b = bh >> 4;
  const int h = bh & 15;
  const int lane = threadIdx.x & 63;
  const int wave = threadIdx.x >> 6;
  const int t0 = tch * 256 + wave * 64;

  const bf16* kvp = kvb + (size_t)bh * 5120;
  bf16x8 bfrag[5][2];
#pragma unroll
  for (int j = 0; j < 5; j++)
#pragma unroll
    for (int kk = 0; kk < 2; kk++)
      bfrag[j][kk] = *(const bf16x8*)(kvp + (j * 16 + (lane & 15)) * 64 + kk * 32 + (lane >> 4) * 8);

  f32x4 acc[4][5] = {};
#pragma unroll
  for (int i = 0; i < 4; i++) {
    const int t = t0 + i * 16 + (lane & 15);
    const bf16* qp = qkv + (size_t)(b * T_ + t) * 3072 + h * 64 + (lane >> 4) * 8;
    bf16x8 a0 = *(const bf16x8*)qp;
    bf16x8 a1 = *(const bf16x8*)(qp + 32);
#pragma unroll
    for (int j = 0; j < 5; j++) {
      acc[i][j] = __builtin_amdgcn_mfma_f32_16x16x32_bf16(a0, bfrag[j][0], acc[i][j], 0, 0, 0);
      acc[i][j] = __builtin_amdgcn_mfma_f32_16x16x32_bf16(a1, bfrag[j][1], acc[i][j], 0, 0, 0);
    }
  }

#pragma unroll
  for (int i = 0; i < 4; i++) {
#pragma unroll
    for (int r = 0; r < 4; r++) {
      float hi = __shfl(acc[i][4][r], (lane & 48));
      float lo = __shfl(acc[i][4][r], (lane & 48) + 1);
      float inv = 1.0f / (hi + lo + EPS_);
      const int t = t0 + i * 16 + (lane >> 4) * 4 + r;
      bf16* op = attn + (size_t)(b * T_ + t) * 1024 + h * 64 + (lane & 15);
#pragma unroll
      for (int j = 0; j < 4; j++)
        op[j * 16] = (bf16)(acc[i][j][r] * inv);
    }
  }
}

// ---------------- launch ----------------
extern "C" void kernel_launch(void* const* d_in, const int* in_sizes, int n_in,
                              void* d_out, int out_size, void* d_ws, size_t ws_size,
                              hipStream_t stream) {
  const float* x = (const float*)d_in[0];
  const float* Wqkv = (const float*)d_in[1];
  const float* Wproj = (const float*)d_in[2];
  const float* bproj = (const float*)d_in[3];
  float* out = (float*)d_out;

  char* w = (char*)d_ws;
  bf16* xw = (bf16*)w;      w += (size_t)16777216 * 2;
  bf16* wqkv = (bf16*)w;    w += (size_t)3145728 * 2;
  bf16* wproj = (bf16*)w;   w += (size_t)1048576 * 2;
  bf16* qkv = (bf16*)w;     w += (size_t)50331648 * 2;
  bf16* attn = (bf16*)w;    w += (size_t)16777216 * 2;
  float* partial = (float*)w; w += (size_t)NCH * 64 * 4160 * 4;
  bf16* kvb = (bf16*)w;

  (void)hipFuncSetAttribute((const void*)gemm3p<0>,
      hipFuncAttributeMaxDynamicSharedMemorySize, SMEMBYTES);
  (void)hipFuncSetAttribute((const void*)gemm3p<1>,
      hipFuncAttributeMaxDynamicSharedMemorySize, SMEMBYTES);

  cast_kernel<<<8192, 256, 0, stream>>>(x, xw, 16777216 / 8);
  cast_kernel<<<1536, 256, 0, stream>>>(Wqkv, wqkv, 3145728 / 8);
  cast_kernel<<<512, 256, 0, stream>>>(Wproj, wproj, 1048576 / 8);

  // qkv = x @ Wqkv^T, phi fused on q,k   (16384x3072x1024): 64 x 24 = 1536 blocks
  gemm3p<0><<<1536, 512, SMEMBYTES, stream>>>(xw, wqkv, (void*)qkv, nullptr, 16384, 3072, 1024, 24);

  kv_kernel<<<NCH * 64, 256, 0, stream>>>(qkv, partial);
  kv_reduce_b<<<(64 * 80 * 64 + 255) / 256, 256, 0, stream>>>(partial, kvb);

  attn_mfma<<<64 * 16, 256, 0, stream>>>(qkv, kvb, attn);

  // out = attn @ Wproj^T + bproj   (16384x1024x1024): 64 x 8 = 512 blocks
  gemm3p<1><<<512, 512, SMEMBYTES, stream>>>(attn, wproj, (void*)out, bproj, 16384, 1024, 1024, 8);
}